// Round 2
// baseline (1567.042 us; speedup 1.0000x reference)
//
#include <hip/hip_runtime.h>
#include <hip/hip_bf16.h>
#include <math.h>

#define BB 4
#define WW 12
#define NN 1024
#define FIN 32
#define FOUT 32
#define HH 256
#define DD 32768     // N*FOUT
#define RR 48        // B*W
#define NCH 64       // k-chunks in projection (512 k each)

// ---------------- K1: d[r][i] = rsqrt(1 + sum_j shots[r][i][j]) ----------------
__global__ __launch_bounds__(256) void k_rowsum(const float* __restrict__ shots,
                                                float* __restrict__ d_arr) {
    int wave = (blockIdx.x * blockDim.x + threadIdx.x) >> 6;  // one wave per row
    int lane = threadIdx.x & 63;
    const float4* row = (const float4*)(shots + (size_t)wave * NN);
    float s = 0.f;
#pragma unroll
    for (int q = 0; q < 4; ++q) {
        float4 v = row[lane + q * 64];
        s += v.x + v.y + v.z + v.w;
    }
#pragma unroll
    for (int off = 32; off; off >>= 1) s += __shfl_xor(s, off, 64);
    if (lane == 0) d_arr[wave] = rsqrtf(s + 1.0f);
}

// ---------------- K2: tmp2[r][j][f] = d[r][j] * sum_k node[r][j][k]*gw[w][k][f] --
__global__ __launch_bounds__(256) void k_tmp2(const float* __restrict__ node,
                                              const float* __restrict__ gw,
                                              const float* __restrict__ d_arr,
                                              float* __restrict__ tmp2) {
    int r  = blockIdx.x >> 7;   // 0..47
    int jg = blockIdx.x & 127;  // 0..127
    int w  = r % WW;
    __shared__ float gwl[32 * 32];
#pragma unroll
    for (int q = 0; q < 4; ++q)
        gwl[threadIdx.x + q * 256] = gw[w * 1024 + threadIdx.x + q * 256];
    __syncthreads();
    int f  = threadIdx.x & 31;
    int jj = threadIdx.x >> 5;  // 0..7
    int j  = jg * 8 + jj;
    const float* nrow = node + ((size_t)r * NN + j) * FIN;
    float acc = 0.f;
#pragma unroll
    for (int k = 0; k < 32; ++k) acc = fmaf(nrow[k], gwl[k * 32 + f], acc);
    tmp2[((size_t)r * NN + j) * 32 + f] = d_arr[r * NN + j] * acc;
}

// ---------------- K3: x[w][b][i*32+f] = d[i]*(sum_j shots[i][j]*tmp2[j][f] + tmp2[i][f])
__global__ __launch_bounds__(512) void k_gcn(const float* __restrict__ shots,
                                             const float* __restrict__ tmp2,
                                             const float* __restrict__ d_arr,
                                             float* __restrict__ x) {
    int r  = blockIdx.x >> 3;   // 0..47  (= b*12 + w)
    int it = blockIdx.x & 7;    // 128-row tile
    int b  = r / WW, w = r % WW;
    int f  = threadIdx.x & 31;
    int rg = threadIdx.x >> 5;  // 0..15
    int i0 = it * 128 + rg * 8;
    const float*  t2    = tmp2 + (size_t)r * NN * 32;
    const float4* sbase = (const float4*)(shots + (size_t)r * NN * NN);
    float acc[8];
#pragma unroll
    for (int rr = 0; rr < 8; ++rr) acc[rr] = t2[(i0 + rr) * 32 + f];  // self-loop term
    const float* t2f = t2 + f;
    for (int j4 = 0; j4 < 256; ++j4) {
        float tv0 = t2f[(j4 * 4 + 0) * 32];
        float tv1 = t2f[(j4 * 4 + 1) * 32];
        float tv2 = t2f[(j4 * 4 + 2) * 32];
        float tv3 = t2f[(j4 * 4 + 3) * 32];
#pragma unroll
        for (int rr = 0; rr < 8; ++rr) {
            float4 a = sbase[(size_t)(i0 + rr) * 256 + j4];
            acc[rr] = fmaf(a.x, tv0, acc[rr]);
            acc[rr] = fmaf(a.y, tv1, acc[rr]);
            acc[rr] = fmaf(a.z, tv2, acc[rr]);
            acc[rr] = fmaf(a.w, tv3, acc[rr]);
        }
    }
    float* xout = x + ((size_t)w * BB + b) * DD;
#pragma unroll
    for (int rr = 0; rr < 8; ++rr) {
        int i = i0 + rr;
        xout[i * 32 + f] = d_arr[r * NN + i] * acc[rr];
    }
}

// ---------------- K4: partial[ch][s][c] = sum_{k in chunk} x[s][k]*w_ih[c][k] ----
// LDS-staged: w-tile loaded coalesced, read back per-thread-row with stride-33
// padding (bank = (33*tid + k) % 32 -> conflict-free). x loads are wave-uniform.
__global__ __launch_bounds__(256, 1) void k_proj(const float* __restrict__ x,
                                                 const float* __restrict__ wih,
                                                 float* __restrict__ partial) {
    __shared__ float ws[256 * 33];  // 33.8 KB
    const int tid = threadIdx.x;
    const int ct  = blockIdx.x & 3;   // c-tile (256 columns)
    const int ch  = blockIdx.x >> 2;  // 0..63 k-chunk (512 k each)
    const int c0  = ct * 256;
    const int k0  = ch * 512;
    const int c   = c0 + tid;

    float acc[RR];
#pragma unroll
    for (int s = 0; s < RR; ++s) acc[s] = 0.f;

    for (int kt = 0; kt < 512; kt += 32) {
        // stage w[c0..c0+255][k0+kt .. +31] into LDS, coalesced
#pragma unroll
        for (int q = 0; q < 8; ++q) {
            int idx  = q * 256 + tid;
            int row  = idx >> 3;
            int col4 = (idx & 7) * 4;
            float4 v = *(const float4*)(wih + (size_t)(c0 + row) * DD + k0 + kt + col4);
            float* dst = &ws[row * 33 + col4];
            dst[0] = v.x; dst[1] = v.y; dst[2] = v.z; dst[3] = v.w;
        }
        __syncthreads();
#pragma unroll
        for (int k8 = 0; k8 < 4; ++k8) {
            float wreg[8];
#pragma unroll
            for (int j = 0; j < 8; ++j) wreg[j] = ws[tid * 33 + k8 * 8 + j];
            const int kbase = k0 + kt + k8 * 8;
#pragma unroll
            for (int s = 0; s < RR; ++s) {
                const float4* xp = (const float4*)(x + (size_t)s * DD + kbase);
                float4 xa = xp[0];
                float4 xb = xp[1];
                acc[s] = fmaf(wreg[0], xa.x, acc[s]);
                acc[s] = fmaf(wreg[1], xa.y, acc[s]);
                acc[s] = fmaf(wreg[2], xa.z, acc[s]);
                acc[s] = fmaf(wreg[3], xa.w, acc[s]);
                acc[s] = fmaf(wreg[4], xb.x, acc[s]);
                acc[s] = fmaf(wreg[5], xb.y, acc[s]);
                acc[s] = fmaf(wreg[6], xb.z, acc[s]);
                acc[s] = fmaf(wreg[7], xb.w, acc[s]);
            }
        }
        __syncthreads();
    }
    float* pout = partial + (size_t)ch * (RR * 1024) + c;
#pragma unroll
    for (int s = 0; s < RR; ++s) pout[s * 1024] = acc[s];
}

// ---------------- K5: G[s][c] = sum_ch partial + biases ----------------
__global__ __launch_bounds__(256) void k_reduce(const float* __restrict__ partial,
                                                const float* __restrict__ bih,
                                                const float* __restrict__ bhh,
                                                float* __restrict__ G) {
    int idx = blockIdx.x * 256 + threadIdx.x;  // s*1024 + c
    float s = 0.f;
#pragma unroll 8
    for (int ch = 0; ch < NCH; ++ch) s += partial[(size_t)ch * (RR * 1024) + idx];
    int c = idx & 1023;
    G[idx] = s + bih[c] + bhh[c];
}

// ---------------- K6: LSTM recurrence, one block per batch ----------------
__global__ __launch_bounds__(1024) void k_lstm(const float* __restrict__ G,
                                               const float* __restrict__ whh,
                                               float* __restrict__ hn) {
    int b = blockIdx.x;
    int t = threadIdx.x;
    __shared__ float hs[HH], cs[HH], gb[1024];
    if (t < HH) { hs[t] = 0.f; cs[t] = 0.f; }
    __syncthreads();
    const float4* wrow = (const float4*)(whh + (size_t)t * HH);
    for (int w = 0; w < WW; ++w) {
        float acc = G[(w * BB + b) * 1024 + t];
        const float4* h4 = (const float4*)hs;
#pragma unroll 8
        for (int k4 = 0; k4 < HH / 4; ++k4) {
            float4 wv = wrow[k4];
            float4 hv = h4[k4];
            acc = fmaf(wv.x, hv.x, acc);
            acc = fmaf(wv.y, hv.y, acc);
            acc = fmaf(wv.z, hv.z, acc);
            acc = fmaf(wv.w, hv.w, acc);
        }
        gb[t] = acc;
        __syncthreads();
        if (t < HH) {
            float ig = gb[t], fg = gb[t + 256], gg = gb[t + 512], og = gb[t + 768];
            float si = 1.f / (1.f + __expf(-ig));
            float sf = 1.f / (1.f + __expf(-fg));
            float so = 1.f / (1.f + __expf(-og));
            float cv = sf * cs[t] + si * tanhf(gg);
            float hv = so * tanhf(cv);
            cs[t] = cv;
            hs[t] = hv;
        }
        __syncthreads();
    }
    if (t < HH) hn[b * HH + t] = hs[t];
}

// ---------------- K7: fused f1 GEMV + s1/s2 reduction (LDS-staged f1_w) ----------
__global__ __launch_bounds__(256, 1) void k_head(const float* __restrict__ hn,
                                                 const float* __restrict__ f1w,
                                                 const float* __restrict__ f1b,
                                                 const float* __restrict__ f2w,
                                                 float* __restrict__ s1,
                                                 float* __restrict__ s2) {
    __shared__ float h[BB * HH];
    __shared__ float ws[256 * 33];
    const int tid = threadIdx.x;
    for (int q = tid; q < BB * HH; q += 256) h[q] = hn[q];
    const int c0 = blockIdx.x * 256;
    const int c  = c0 + tid;
    float a0 = 0, a1 = 0, a2 = 0, a3 = 0;
    for (int kt = 0; kt < HH; kt += 32) {
        __syncthreads();
#pragma unroll
        for (int q = 0; q < 8; ++q) {
            int idx  = q * 256 + tid;
            int row  = idx >> 3;
            int col4 = (idx & 7) * 4;
            float4 v = *(const float4*)(f1w + (size_t)(c0 + row) * HH + kt + col4);
            float* dst = &ws[row * 33 + col4];
            dst[0] = v.x; dst[1] = v.y; dst[2] = v.z; dst[3] = v.w;
        }
        __syncthreads();
#pragma unroll
        for (int k8 = 0; k8 < 4; ++k8) {
            float wreg[8];
#pragma unroll
            for (int j = 0; j < 8; ++j) wreg[j] = ws[tid * 33 + k8 * 8 + j];
            const int kb = kt + k8 * 8;
            const float4* h0 = (const float4*)(h + 0 * HH + kb);
            const float4* h1 = (const float4*)(h + 1 * HH + kb);
            const float4* h2 = (const float4*)(h + 2 * HH + kb);
            const float4* h3 = (const float4*)(h + 3 * HH + kb);
            float4 va, vb;
            va = h0[0]; vb = h0[1];
            a0 = fmaf(wreg[0], va.x, a0); a0 = fmaf(wreg[1], va.y, a0);
            a0 = fmaf(wreg[2], va.z, a0); a0 = fmaf(wreg[3], va.w, a0);
            a0 = fmaf(wreg[4], vb.x, a0); a0 = fmaf(wreg[5], vb.y, a0);
            a0 = fmaf(wreg[6], vb.z, a0); a0 = fmaf(wreg[7], vb.w, a0);
            va = h1[0]; vb = h1[1];
            a1 = fmaf(wreg[0], va.x, a1); a1 = fmaf(wreg[1], va.y, a1);
            a1 = fmaf(wreg[2], va.z, a1); a1 = fmaf(wreg[3], va.w, a1);
            a1 = fmaf(wreg[4], vb.x, a1); a1 = fmaf(wreg[5], vb.y, a1);
            a1 = fmaf(wreg[6], vb.z, a1); a1 = fmaf(wreg[7], vb.w, a1);
            va = h2[0]; vb = h2[1];
            a2 = fmaf(wreg[0], va.x, a2); a2 = fmaf(wreg[1], va.y, a2);
            a2 = fmaf(wreg[2], va.z, a2); a2 = fmaf(wreg[3], va.w, a2);
            a2 = fmaf(wreg[4], vb.x, a2); a2 = fmaf(wreg[5], vb.y, a2);
            a2 = fmaf(wreg[6], vb.z, a2); a2 = fmaf(wreg[7], vb.w, a2);
            va = h3[0]; vb = h3[1];
            a3 = fmaf(wreg[0], va.x, a3); a3 = fmaf(wreg[1], va.y, a3);
            a3 = fmaf(wreg[2], va.z, a3); a3 = fmaf(wreg[3], va.w, a3);
            a3 = fmaf(wreg[4], vb.x, a3); a3 = fmaf(wreg[5], vb.y, a3);
            a3 = fmaf(wreg[6], vb.z, a3); a3 = fmaf(wreg[7], vb.w, a3);
        }
    }
    float bias = f1b[c];
    float o0 = a0 + bias, o1 = a1 + bias, o2 = a2 + bias, o3 = a3 + bias;
    int f = c & 31;
    float w1 = f2w[f], w2 = f2w[32 + f];
    float p0 = o0 * w1, p1 = o1 * w1, p2 = o2 * w1, p3 = o3 * w1;
    float q0 = o0 * w2, q1 = o1 * w2, q2 = o2 * w2, q3 = o3 * w2;
#pragma unroll
    for (int off = 16; off; off >>= 1) {
        p0 += __shfl_xor(p0, off, 64); p1 += __shfl_xor(p1, off, 64);
        p2 += __shfl_xor(p2, off, 64); p3 += __shfl_xor(p3, off, 64);
        q0 += __shfl_xor(q0, off, 64); q1 += __shfl_xor(q1, off, 64);
        q2 += __shfl_xor(q2, off, 64); q3 += __shfl_xor(q3, off, 64);
    }
    if (f == 0) {
        int n = c >> 5;
        s1[0 * NN + n] = p0; s1[1 * NN + n] = p1;
        s1[2 * NN + n] = p2; s1[3 * NN + n] = p3;
        s2[0 * NN + n] = q0; s2[1 * NN + n] = q1;
        s2[2 * NN + n] = q2; s2[3 * NN + n] = q3;
    }
}

// ---------------- K8: scores + keep + L1 normalize ----------------
__global__ __launch_bounds__(256) void k_score(const float* __restrict__ s1,
                                               const float* __restrict__ s2,
                                               const float* __restrict__ f2b,
                                               float* __restrict__ out) {
    int bi = blockIdx.x;  // b*1024 + i
    int b = bi >> 10, i = bi & 1023;
    float fb  = f2b[0];
    float s1i = s1[b * NN + i];
    float s2i = s2[b * NN + i];
    __shared__ float red[4];
    float vals[4];
    float asum = 0.f;
#pragma unroll
    for (int q = 0; q < 4; ++q) {
        int j = q * 256 + threadIdx.x;
        float sc = s1i + s2[b * NN + j] + fb;
        float st = s1[b * NN + j] + s2i + fb;
        bool keep;
        if (i == j)      keep = true;
        else if (i < j)  keep = (sc >= st) && (sc > 0.f);
        else             keep = (sc > st) && (sc >= 0.f);
        float v = keep ? sc : 0.f;
        vals[q] = v;
        asum += fabsf(v);
    }
#pragma unroll
    for (int off = 32; off; off >>= 1) asum += __shfl_xor(asum, off, 64);
    int lane = threadIdx.x & 63, wv = threadIdx.x >> 6;
    if (lane == 0) red[wv] = asum;
    __syncthreads();
    float tot = red[0] + red[1] + red[2] + red[3];
    float inv = 1.f / fmaxf(tot, 1e-12f);
    float* orow = out + (size_t)bi * NN;
#pragma unroll
    for (int q = 0; q < 4; ++q) orow[q * 256 + threadIdx.x] = vals[q] * inv;
}

extern "C" void kernel_launch(void* const* d_in, const int* in_sizes, int n_in,
                              void* d_out, int out_size, void* d_ws, size_t ws_size,
                              hipStream_t stream) {
    const float* in_shots = (const float*)d_in[0];
    const float* in_node  = (const float*)d_in[1];
    // d_in[2] = 'a' (unused by reference)
    const float* gcn_w    = (const float*)d_in[3];
    const float* w_ih     = (const float*)d_in[4];
    const float* w_hh     = (const float*)d_in[5];
    const float* b_ih     = (const float*)d_in[6];
    const float* b_hh     = (const float*)d_in[7];
    const float* f1_w     = (const float*)d_in[8];
    const float* f1_b     = (const float*)d_in[9];
    const float* f2_w     = (const float*)d_in[10];
    const float* f2_b     = (const float*)d_in[11];
    float* out = (float*)d_out;

    float* wsf    = (float*)d_ws;
    float* d_arr  = wsf;                         // 48*1024
    float* tmp2   = wsf + 49152;                 // 48*1024*32
    float* x      = wsf + 49152 + 1572864;       // 12*4*32768
    float* part   = x + 1572864;                 // 64*48*1024
    float* G      = part + NCH * RR * 1024;      // 48*1024
    float* hn     = G + 49152;                   // 4*256
    float* s1     = hn + 1024;                   // 4*1024
    float* s2     = s1 + 4096;                   // 4*1024

    k_rowsum<<<RR * NN / 4, 256, 0, stream>>>(in_shots, d_arr);
    k_tmp2  <<<RR * 128,    256, 0, stream>>>(in_node, gcn_w, d_arr, tmp2);
    k_gcn   <<<RR * 8,      512, 0, stream>>>(in_shots, tmp2, d_arr, x);
    k_proj  <<<4 * NCH,     256, 0, stream>>>(x, w_ih, part);
    k_reduce<<<RR * 1024 / 256, 256, 0, stream>>>(part, b_ih, b_hh, G);
    k_lstm  <<<BB,          1024, 0, stream>>>(G, w_hh, hn);
    k_head  <<<DD / 256,    256, 0, stream>>>(hn, f1_w, f1_b, f2_w, s1, s2);
    k_score <<<BB * NN,     256, 0, stream>>>(s1, s2, f2_b, out);
}

// Round 4
// 912.840 us; speedup vs baseline: 1.7167x; 1.7167x over previous
//
#include <hip/hip_runtime.h>
#include <hip/hip_bf16.h>
#include <math.h>

#define BB 4
#define WW 12
#define NN 1024
#define FIN 32
#define FOUT 32
#define HH 256
#define DD 32768     // N*FOUT
#define RR 48        // B*W
#define NCH 64       // k-chunks in projection (512 k each)

// ---------------- K1: d[r][i] = rsqrt(1 + sum_j shots[r][i][j]) ----------------
__global__ __launch_bounds__(256) void k_rowsum(const float* __restrict__ shots,
                                                float* __restrict__ d_arr) {
    int wave = (blockIdx.x * blockDim.x + threadIdx.x) >> 6;  // one wave per row
    int lane = threadIdx.x & 63;
    const float4* row = (const float4*)(shots + (size_t)wave * NN);
    float s = 0.f;
#pragma unroll
    for (int q = 0; q < 4; ++q) {
        float4 v = row[lane + q * 64];
        s += v.x + v.y + v.z + v.w;
    }
#pragma unroll
    for (int off = 32; off; off >>= 1) s += __shfl_xor(s, off, 64);
    if (lane == 0) d_arr[wave] = rsqrtf(s + 1.0f);
}

// ---------------- K2: tmp2[r][j][f] = d[r][j] * sum_k node[r][j][k]*gw[w][k][f] --
__global__ __launch_bounds__(256) void k_tmp2(const float* __restrict__ node,
                                              const float* __restrict__ gw,
                                              const float* __restrict__ d_arr,
                                              float* __restrict__ tmp2) {
    int r  = blockIdx.x >> 7;   // 0..47
    int jg = blockIdx.x & 127;  // 0..127
    int w  = r % WW;
    __shared__ float gwl[32 * 32];
#pragma unroll
    for (int q = 0; q < 4; ++q)
        gwl[threadIdx.x + q * 256] = gw[w * 1024 + threadIdx.x + q * 256];
    __syncthreads();
    int f  = threadIdx.x & 31;
    int jj = threadIdx.x >> 5;  // 0..7
    int j  = jg * 8 + jj;
    const float* nrow = node + ((size_t)r * NN + j) * FIN;
    float acc = 0.f;
#pragma unroll
    for (int k = 0; k < 32; ++k) acc = fmaf(nrow[k], gwl[k * 32 + f], acc);
    tmp2[((size_t)r * NN + j) * 32 + f] = d_arr[r * NN + j] * acc;
}

// ---------------- K3: register-tiled GEMM per r: adj-row dot tmp2 ----------------
// Block: one r (0..47) x one 128-row i-tile. Thread tile 4i x 4f.
// Tile 128x64 = 2048 float4 -> q<8 staging iterations (q<32 was the R3 crash).
#define SLD 68   // shots tile row stride (words), 16B-aligned
__global__ __launch_bounds__(256) void k_gcn(const float* __restrict__ shots,
                                             const float* __restrict__ tmp2,
                                             const float* __restrict__ d_arr,
                                             float* __restrict__ x) {
    __shared__ float ssm[128 * SLD];  // 34.8 KB
    __shared__ float tsm[64 * 32];    // 8 KB
    const int tid = threadIdx.x;
    const int r   = blockIdx.x >> 3;   // 0..47  (= b*12 + w)
    const int it  = blockIdx.x & 7;    // 128-row tile
    const int b   = r / WW, w = r % WW;
    const int fg  = tid & 7;           // f4 = fg*4
    const int ig  = tid >> 3;          // 0..31, i = it*128 + ig*4 + ii
    const int f4  = fg * 4;
    const int i0  = it * 128 + ig * 4;

    float acc[4][4];
#pragma unroll
    for (int ii = 0; ii < 4; ++ii)
#pragma unroll
        for (int ff = 0; ff < 4; ++ff) acc[ii][ff] = 0.f;

    const float* sg_base = shots + ((size_t)r * NN + it * 128) * NN;
    const float* t_base  = tmp2 + (size_t)r * NN * 32;

    for (int jt = 0; jt < NN; jt += 64) {
        __syncthreads();
        // stage shots[i-tile][jt..jt+63]  (128x64 floats = 2048 float4, coalesced)
#pragma unroll
        for (int q = 0; q < 8; ++q) {
            int idx  = q * 256 + tid;
            int row  = idx >> 4;          // 16 float4 per row
            int col4 = (idx & 15) * 4;
            float4 v = *(const float4*)(sg_base + (size_t)row * NN + jt + col4);
            float* dst = &ssm[row * SLD + col4];
            dst[0] = v.x; dst[1] = v.y; dst[2] = v.z; dst[3] = v.w;
        }
        // stage tmp2[jt..jt+63][0..31]  (64x32 floats = 512 float4)
#pragma unroll
        for (int q = 0; q < 2; ++q) {
            int idx  = q * 256 + tid;
            int row  = idx >> 3;
            int col4 = (idx & 7) * 4;
            float4 v = *(const float4*)(t_base + (size_t)(jt + row) * 32 + col4);
            float* dst = &tsm[row * 32 + col4];
            dst[0] = v.x; dst[1] = v.y; dst[2] = v.z; dst[3] = v.w;
        }
        __syncthreads();
#pragma unroll 4
        for (int j4 = 0; j4 < 64; j4 += 4) {
            float4 sf[4], tf[4];
#pragma unroll
            for (int ii = 0; ii < 4; ++ii)
                sf[ii] = *(const float4*)&ssm[(ig * 4 + ii) * SLD + j4];
#pragma unroll
            for (int jj = 0; jj < 4; ++jj)
                tf[jj] = *(const float4*)&tsm[(j4 + jj) * 32 + f4];
#pragma unroll
            for (int ii = 0; ii < 4; ++ii) {
                acc[ii][0] = fmaf(sf[ii].x, tf[0].x, acc[ii][0]);
                acc[ii][1] = fmaf(sf[ii].x, tf[0].y, acc[ii][1]);
                acc[ii][2] = fmaf(sf[ii].x, tf[0].z, acc[ii][2]);
                acc[ii][3] = fmaf(sf[ii].x, tf[0].w, acc[ii][3]);
                acc[ii][0] = fmaf(sf[ii].y, tf[1].x, acc[ii][0]);
                acc[ii][1] = fmaf(sf[ii].y, tf[1].y, acc[ii][1]);
                acc[ii][2] = fmaf(sf[ii].y, tf[1].z, acc[ii][2]);
                acc[ii][3] = fmaf(sf[ii].y, tf[1].w, acc[ii][3]);
                acc[ii][0] = fmaf(sf[ii].z, tf[2].x, acc[ii][0]);
                acc[ii][1] = fmaf(sf[ii].z, tf[2].y, acc[ii][1]);
                acc[ii][2] = fmaf(sf[ii].z, tf[2].z, acc[ii][2]);
                acc[ii][3] = fmaf(sf[ii].z, tf[2].w, acc[ii][3]);
                acc[ii][0] = fmaf(sf[ii].w, tf[3].x, acc[ii][0]);
                acc[ii][1] = fmaf(sf[ii].w, tf[3].y, acc[ii][1]);
                acc[ii][2] = fmaf(sf[ii].w, tf[3].z, acc[ii][2]);
                acc[ii][3] = fmaf(sf[ii].w, tf[3].w, acc[ii][3]);
            }
        }
    }
    // epilogue: add self-loop term, scale by d[i], write x time-major
    float* xout = x + ((size_t)w * BB + b) * DD;
#pragma unroll
    for (int ii = 0; ii < 4; ++ii) {
        int i = i0 + ii;
        float di = d_arr[r * NN + i];
        float4 selfv = *(const float4*)(t_base + (size_t)i * 32 + f4);
        float4 o;
        o.x = di * (acc[ii][0] + selfv.x);
        o.y = di * (acc[ii][1] + selfv.y);
        o.z = di * (acc[ii][2] + selfv.z);
        o.w = di * (acc[ii][3] + selfv.w);
        *(float4*)(xout + (size_t)i * 32 + f4) = o;
    }
}

// ---------------- K4: register-tiled GEMM: partial[ch] = x @ w_ih_chunk^T -------
// Block: 128-c tile x 512-k chunk. Thread tile 6s x 4c. LDS b128 conflict-free.
#define WLD 36   // w tile row stride (words), 16B-aligned
__global__ __launch_bounds__(256) void k_proj(const float* __restrict__ x,
                                              const float* __restrict__ wih,
                                              float* __restrict__ partial) {
    __shared__ float wsm[128 * WLD];  // 18.4 KB
    __shared__ float xsm[48 * WLD];   // 6.9 KB
    const int tid = threadIdx.x;
    const int ct  = blockIdx.x & 7;   // c-tile (128 cols)
    const int ch  = blockIdx.x >> 3;  // 0..63 k-chunk (512 k)
    const int c0  = ct * 128;
    const int k0  = ch * 512;
    const int cg  = tid & 31;         // c = c0 + cg + 32*j
    const int sg  = tid >> 5;         // s = sg*6 + ss

    float acc[6][4];
#pragma unroll
    for (int ss = 0; ss < 6; ++ss)
#pragma unroll
        for (int j = 0; j < 4; ++j) acc[ss][j] = 0.f;

    for (int kt = 0; kt < 512; kt += 32) {
        __syncthreads();
        // stage w[c0..c0+127][k0+kt .. +31]  (128x32 = 1024 float4, coalesced)
#pragma unroll
        for (int q = 0; q < 4; ++q) {
            int idx  = q * 256 + tid;
            int row  = idx >> 3;
            int col4 = (idx & 7) * 4;
            float4 v = *(const float4*)(wih + (size_t)(c0 + row) * DD + k0 + kt + col4);
            float* dst = &wsm[row * WLD + col4];
            dst[0] = v.x; dst[1] = v.y; dst[2] = v.z; dst[3] = v.w;
        }
        // stage x[0..47][k0+kt .. +31]  (48x32 = 384 float4)
#pragma unroll
        for (int q = 0; q < 2; ++q) {
            int idx = q * 256 + tid;
            if (idx < 384) {
                int row  = idx >> 3;
                int col4 = (idx & 7) * 4;
                float4 v = *(const float4*)(x + (size_t)row * DD + k0 + kt + col4);
                float* dst = &xsm[row * WLD + col4];
                dst[0] = v.x; dst[1] = v.y; dst[2] = v.z; dst[3] = v.w;
            }
        }
        __syncthreads();
#pragma unroll 4
        for (int k4 = 0; k4 < 32; k4 += 4) {
            float4 wf[4], xf[6];
#pragma unroll
            for (int j = 0; j < 4; ++j)
                wf[j] = *(const float4*)&wsm[(cg + 32 * j) * WLD + k4];
#pragma unroll
            for (int ss = 0; ss < 6; ++ss)
                xf[ss] = *(const float4*)&xsm[(sg * 6 + ss) * WLD + k4];
#pragma unroll
            for (int ss = 0; ss < 6; ++ss)
#pragma unroll
                for (int j = 0; j < 4; ++j) {
                    acc[ss][j] = fmaf(xf[ss].x, wf[j].x, acc[ss][j]);
                    acc[ss][j] = fmaf(xf[ss].y, wf[j].y, acc[ss][j]);
                    acc[ss][j] = fmaf(xf[ss].z, wf[j].z, acc[ss][j]);
                    acc[ss][j] = fmaf(xf[ss].w, wf[j].w, acc[ss][j]);
                }
        }
    }
    float* pout = partial + (size_t)ch * (RR * 1024);
#pragma unroll
    for (int ss = 0; ss < 6; ++ss)
#pragma unroll
        for (int j = 0; j < 4; ++j)
            pout[(sg * 6 + ss) * 1024 + c0 + cg + 32 * j] = acc[ss][j];
}

// ---------------- K5: G[s][c] = sum_ch partial + biases ----------------
__global__ __launch_bounds__(256) void k_reduce(const float* __restrict__ partial,
                                                const float* __restrict__ bih,
                                                const float* __restrict__ bhh,
                                                float* __restrict__ G) {
    int idx = blockIdx.x * 256 + threadIdx.x;  // s*1024 + c
    float s = 0.f;
#pragma unroll 8
    for (int ch = 0; ch < NCH; ++ch) s += partial[(size_t)ch * (RR * 1024) + idx];
    int c = idx & 1023;
    G[idx] = s + bih[c] + bhh[c];
}

// ---------------- K6: LSTM recurrence, one block per batch ----------------
__global__ __launch_bounds__(1024) void k_lstm(const float* __restrict__ G,
                                               const float* __restrict__ whh,
                                               float* __restrict__ hn) {
    int b = blockIdx.x;
    int t = threadIdx.x;
    __shared__ float hs[HH], cs[HH], gb[1024];
    if (t < HH) { hs[t] = 0.f; cs[t] = 0.f; }
    __syncthreads();
    const float4* wrow = (const float4*)(whh + (size_t)t * HH);
    for (int w = 0; w < WW; ++w) {
        float acc = G[(w * BB + b) * 1024 + t];
        const float4* h4 = (const float4*)hs;
#pragma unroll 8
        for (int k4 = 0; k4 < HH / 4; ++k4) {
            float4 wv = wrow[k4];
            float4 hv = h4[k4];
            acc = fmaf(wv.x, hv.x, acc);
            acc = fmaf(wv.y, hv.y, acc);
            acc = fmaf(wv.z, hv.z, acc);
            acc = fmaf(wv.w, hv.w, acc);
        }
        gb[t] = acc;
        __syncthreads();
        if (t < HH) {
            float ig = gb[t], fg = gb[t + 256], gg = gb[t + 512], og = gb[t + 768];
            float si = 1.f / (1.f + __expf(-ig));
            float sf = 1.f / (1.f + __expf(-fg));
            float so = 1.f / (1.f + __expf(-og));
            float cv = sf * cs[t] + si * tanhf(gg);
            float hv = so * tanhf(cv);
            cs[t] = cv;
            hs[t] = hv;
        }
        __syncthreads();
    }
    if (t < HH) hn[b * HH + t] = hs[t];
}

// ---------------- K7: fused f1 GEMV + s1/s2 reduction (LDS-staged f1_w) ----------
__global__ __launch_bounds__(256, 1) void k_head(const float* __restrict__ hn,
                                                 const float* __restrict__ f1w,
                                                 const float* __restrict__ f1b,
                                                 const float* __restrict__ f2w,
                                                 float* __restrict__ s1,
                                                 float* __restrict__ s2) {
    __shared__ float h[BB * HH];
    __shared__ float ws[256 * 33];
    const int tid = threadIdx.x;
    for (int q = tid; q < BB * HH; q += 256) h[q] = hn[q];
    const int c0 = blockIdx.x * 256;
    const int c  = c0 + tid;
    float a0 = 0, a1 = 0, a2 = 0, a3 = 0;
    for (int kt = 0; kt < HH; kt += 32) {
        __syncthreads();
#pragma unroll
        for (int q = 0; q < 8; ++q) {
            int idx  = q * 256 + tid;
            int row  = idx >> 3;
            int col4 = (idx & 7) * 4;
            float4 v = *(const float4*)(f1w + (size_t)(c0 + row) * HH + kt + col4);
            float* dst = &ws[row * 33 + col4];
            dst[0] = v.x; dst[1] = v.y; dst[2] = v.z; dst[3] = v.w;
        }
        __syncthreads();
#pragma unroll
        for (int k8 = 0; k8 < 4; ++k8) {
            float wreg[8];
#pragma unroll
            for (int j = 0; j < 8; ++j) wreg[j] = ws[tid * 33 + k8 * 8 + j];
            const int kb = kt + k8 * 8;
            const float4* h0 = (const float4*)(h + 0 * HH + kb);
            const float4* h1 = (const float4*)(h + 1 * HH + kb);
            const float4* h2 = (const float4*)(h + 2 * HH + kb);
            const float4* h3 = (const float4*)(h + 3 * HH + kb);
            float4 va, vb;
            va = h0[0]; vb = h0[1];
            a0 = fmaf(wreg[0], va.x, a0); a0 = fmaf(wreg[1], va.y, a0);
            a0 = fmaf(wreg[2], va.z, a0); a0 = fmaf(wreg[3], va.w, a0);
            a0 = fmaf(wreg[4], vb.x, a0); a0 = fmaf(wreg[5], vb.y, a0);
            a0 = fmaf(wreg[6], vb.z, a0); a0 = fmaf(wreg[7], vb.w, a0);
            va = h1[0]; vb = h1[1];
            a1 = fmaf(wreg[0], va.x, a1); a1 = fmaf(wreg[1], va.y, a1);
            a1 = fmaf(wreg[2], va.z, a1); a1 = fmaf(wreg[3], va.w, a1);
            a1 = fmaf(wreg[4], vb.x, a1); a1 = fmaf(wreg[5], vb.y, a1);
            a1 = fmaf(wreg[6], vb.z, a1); a1 = fmaf(wreg[7], vb.w, a1);
            va = h2[0]; vb = h2[1];
            a2 = fmaf(wreg[0], va.x, a2); a2 = fmaf(wreg[1], va.y, a2);
            a2 = fmaf(wreg[2], va.z, a2); a2 = fmaf(wreg[3], va.w, a2);
            a2 = fmaf(wreg[4], vb.x, a2); a2 = fmaf(wreg[5], vb.y, a2);
            a2 = fmaf(wreg[6], vb.z, a2); a2 = fmaf(wreg[7], vb.w, a2);
            va = h3[0]; vb = h3[1];
            a3 = fmaf(wreg[0], va.x, a3); a3 = fmaf(wreg[1], va.y, a3);
            a3 = fmaf(wreg[2], va.z, a3); a3 = fmaf(wreg[3], va.w, a3);
            a3 = fmaf(wreg[4], vb.x, a3); a3 = fmaf(wreg[5], vb.y, a3);
            a3 = fmaf(wreg[6], vb.z, a3); a3 = fmaf(wreg[7], vb.w, a3);
        }
    }
    float bias = f1b[c];
    float o0 = a0 + bias, o1 = a1 + bias, o2 = a2 + bias, o3 = a3 + bias;
    int f = c & 31;
    float w1 = f2w[f], w2 = f2w[32 + f];
    float p0 = o0 * w1, p1 = o1 * w1, p2 = o2 * w1, p3 = o3 * w1;
    float q0 = o0 * w2, q1 = o1 * w2, q2 = o2 * w2, q3 = o3 * w2;
#pragma unroll
    for (int off = 16; off; off >>= 1) {
        p0 += __shfl_xor(p0, off, 64); p1 += __shfl_xor(p1, off, 64);
        p2 += __shfl_xor(p2, off, 64); p3 += __shfl_xor(p3, off, 64);
        q0 += __shfl_xor(q0, off, 64); q1 += __shfl_xor(q1, off, 64);
        q2 += __shfl_xor(q2, off, 64); q3 += __shfl_xor(q3, off, 64);
    }
    if (f == 0) {
        int n = c >> 5;
        s1[0 * NN + n] = p0; s1[1 * NN + n] = p1;
        s1[2 * NN + n] = p2; s1[3 * NN + n] = p3;
        s2[0 * NN + n] = q0; s2[1 * NN + n] = q1;
        s2[2 * NN + n] = q2; s2[3 * NN + n] = q3;
    }
}

// ---------------- K8: scores + keep + L1 normalize ----------------
__global__ __launch_bounds__(256) void k_score(const float* __restrict__ s1,
                                               const float* __restrict__ s2,
                                               const float* __restrict__ f2b,
                                               float* __restrict__ out) {
    int bi = blockIdx.x;  // b*1024 + i
    int b = bi >> 10, i = bi & 1023;
    float fb  = f2b[0];
    float s1i = s1[b * NN + i];
    float s2i = s2[b * NN + i];
    __shared__ float red[4];
    float vals[4];
    float asum = 0.f;
#pragma unroll
    for (int q = 0; q < 4; ++q) {
        int j = q * 256 + threadIdx.x;
        float sc = s1i + s2[b * NN + j] + fb;
        float st = s1[b * NN + j] + s2i + fb;
        bool keep;
        if (i == j)      keep = true;
        else if (i < j)  keep = (sc >= st) && (sc > 0.f);
        else             keep = (sc > st) && (sc >= 0.f);
        float v = keep ? sc : 0.f;
        vals[q] = v;
        asum += fabsf(v);
    }
#pragma unroll
    for (int off = 32; off; off >>= 1) asum += __shfl_xor(asum, off, 64);
    int lane = threadIdx.x & 63, wv = threadIdx.x >> 6;
    if (lane == 0) red[wv] = asum;
    __syncthreads();
    float tot = red[0] + red[1] + red[2] + red[3];
    float inv = 1.f / fmaxf(tot, 1e-12f);
    float* orow = out + (size_t)bi * NN;
#pragma unroll
    for (int q = 0; q < 4; ++q) orow[q * 256 + threadIdx.x] = vals[q] * inv;
}

extern "C" void kernel_launch(void* const* d_in, const int* in_sizes, int n_in,
                              void* d_out, int out_size, void* d_ws, size_t ws_size,
                              hipStream_t stream) {
    const float* in_shots = (const float*)d_in[0];
    const float* in_node  = (const float*)d_in[1];
    // d_in[2] = 'a' (unused by reference)
    const float* gcn_w    = (const float*)d_in[3];
    const float* w_ih     = (const float*)d_in[4];
    const float* w_hh     = (const float*)d_in[5];
    const float* b_ih     = (const float*)d_in[6];
    const float* b_hh     = (const float*)d_in[7];
    const float* f1_w     = (const float*)d_in[8];
    const float* f1_b     = (const float*)d_in[9];
    const float* f2_w     = (const float*)d_in[10];
    const float* f2_b     = (const float*)d_in[11];
    float* out = (float*)d_out;

    float* wsf    = (float*)d_ws;
    float* d_arr  = wsf;                         // 48*1024
    float* tmp2   = wsf + 49152;                 // 48*1024*32
    float* x      = wsf + 49152 + 1572864;       // 12*4*32768
    float* part   = x + 1572864;                 // 64*48*1024
    float* G      = part + NCH * RR * 1024;      // 48*1024
    float* hn     = G + 49152;                   // 4*256
    float* s1     = hn + 1024;                   // 4*1024
    float* s2     = s1 + 4096;                   // 4*1024

    k_rowsum<<<RR * NN / 4, 256, 0, stream>>>(in_shots, d_arr);
    k_tmp2  <<<RR * 128,    256, 0, stream>>>(in_node, gcn_w, d_arr, tmp2);
    k_gcn   <<<RR * 8,      256, 0, stream>>>(in_shots, tmp2, d_arr, x);
    k_proj  <<<8 * NCH,     256, 0, stream>>>(x, w_ih, part);
    k_reduce<<<RR * 1024 / 256, 256, 0, stream>>>(part, b_ih, b_hh, G);
    k_lstm  <<<BB,          1024, 0, stream>>>(G, w_hh, hn);
    k_head  <<<DD / 256,    256, 0, stream>>>(hn, f1_w, f1_b, f2_w, s1, s2);
    k_score <<<BB * NN,     256, 0, stream>>>(s1, s2, f2_b, out);
}